// Round 1
// baseline (757.551 us; speedup 1.0000x reference)
//
#include <hip/hip_runtime.h>
#include <math.h>

#define NN 2048
#define TT 32
#define FIN 5
#define HH 64
#define G4 256     // 4*H
#define GATH 16
#define CAP 256    // max CSC edges/column: mean 102, sigma ~10 -> +15 sigma safe

// ---------- helpers ----------
__device__ __forceinline__ float sigf(float x) {
    return 1.0f / (1.0f + __expf(-x));
}
__device__ __forceinline__ float tanh_fast(float x) {
    x = fminf(fmaxf(x, -15.0f), 15.0f);
    float t = __expf(2.0f * x);
    return (t - 1.0f) / (t + 1.0f);
}
__device__ __forceinline__ float dot4(float4 a, float4 b) {
    return a.x * b.x + a.y * b.y + a.z * b.z + a.w * b.w;
}
__device__ __forceinline__ float lrelu_exp(float x) {
    x = (x > 0.0f) ? x : 0.2f * x;
    return __expf(x);
}

// gate-collect + cell update. v = own gate's full value; x2/x4/x6 = values of
// gates at lane-xor 2/4/6. Mapping: value of gate j sits at xor ((gate^j)<<1).
__device__ __forceinline__ float lstm_combine(float v, float x2, float x4,
                                              float x6, int gate, float& c)
{
    float gi = (gate == 0) ? v  : (gate == 1) ? x2 : (gate == 2) ? x4 : x6;
    float gf = (gate == 0) ? x2 : (gate == 1) ? v  : (gate == 2) ? x6 : x4;
    float gg = (gate == 0) ? x4 : (gate == 1) ? x6 : (gate == 2) ? v  : x2;
    float go = (gate == 0) ? x6 : (gate == 1) ? x4 : (gate == 2) ? x2 : v;
    c = sigf(gf) * c + sigf(gi) * tanh_fast(gg);
    return sigf(go) * tanh_fast(c);
}

// ---------- fused 2-layer LSTM ----------
// R8: 512-thread remap. kh=tid&1 (K-half), gate=(tid>>1)&3, cell=tid>>3.
// A cell's 8 contributor lanes are adjacent in one wave -> gate exchange is
// 4 shfl_xor, no g_lds, ONE barrier/step. Per-thread weights: phase A 32+5,
// phase B 64 floats -> fully VGPR-resident under the 128-VGPR cap (the old
// 256-thread version needed 128 weight VGPRs vs VGPR_Count=116 -> in-loop
// weight reloads from L2 every timestep).
#define LNB 2
__global__ __launch_bounds__(512, 4)
void k_lstm(
    const float* __restrict__ inputs,
    const float* __restrict__ w_ih0, const float* __restrict__ w_hh0,
    const float* __restrict__ b_ih0, const float* __restrict__ b_hh0,
    const float* __restrict__ w_ih1, const float* __restrict__ w_hh1,
    const float* __restrict__ b_ih1, const float* __restrict__ b_hh1,
    float* __restrict__ x_out)
{
    __shared__ float x_lds[LNB][TT * FIN];     // 320 f
    __shared__ float hist[LNB][TT + 1][HH];    // 4224 f = 16.9 KB
    __shared__ float h1buf[2][LNB][HH];        // 256 f (ping-pong: 1 barrier/t)

    const int tid  = threadIdx.x;
    const int kh   = tid & 1;          // K-half
    const int gate = (tid >> 1) & 3;   // i/f/g/o
    const int cell = tid >> 3;         // 0..63
    const int row  = gate * HH + cell; // gate row 0..255
    const int n0   = blockIdx.x * LNB;

    for (int idx = tid; idx < LNB * TT * FIN; idx += 512)
        ((float*)x_lds)[idx] = inputs[n0 * (TT * FIN) + idx];
    if (tid < LNB * HH) {
        hist[tid >> 6][0][tid & 63] = 0.0f;
        h1buf[0][tid >> 6][tid & 63] = 0.0f;
    }

    // ================= Phase A: layer 0 =================
    {
        float4 wA[8];
        {
            const float4* p = (const float4*)(w_hh0 + row * HH + kh * 32);
            #pragma unroll
            for (int k = 0; k < 8; ++k) wA[k] = p[k];
        }
        float xw0 = 0.f, xw1 = 0.f, xw2 = 0.f, xw3 = 0.f, xw4 = 0.f;
        float biasA = 0.f;
        if (kh == 0) {
            xw0 = w_ih0[row * FIN + 0];
            xw1 = w_ih0[row * FIN + 1];
            xw2 = w_ih0[row * FIN + 2];
            xw3 = w_ih0[row * FIN + 3];
            xw4 = w_ih0[row * FIN + 4];
            biasA = b_ih0[row] + b_hh0[row];
        }
        float c0[LNB] = {0.0f, 0.0f};

        __syncthreads();

        for (int t = 1; t <= TT; ++t) {
            float vA[LNB];
            #pragma unroll
            for (int nb = 0; nb < LNB; ++nb) {
                const float4* hv = (const float4*)&hist[nb][t - 1][kh * 32];
                float s0 = 0.f, s1 = 0.f, s2 = 0.f, s3 = 0.f;
                #pragma unroll
                for (int k = 0; k < 2; ++k) {
                    s0 += dot4(wA[k],     hv[k]);
                    s1 += dot4(wA[2 + k], hv[2 + k]);
                    s2 += dot4(wA[4 + k], hv[4 + k]);
                    s3 += dot4(wA[6 + k], hv[6 + k]);
                }
                float s = (s0 + s1) + (s2 + s3);
                if (kh == 0) {
                    const float* xv = &x_lds[nb][(t - 1) * FIN];
                    s += biasA + xw0 * xv[0] + xw1 * xv[1] + xw2 * xv[2] +
                         xw3 * xv[3] + xw4 * xv[4];
                }
                vA[nb] = s;
            }
            #pragma unroll
            for (int nb = 0; nb < LNB; ++nb) {
                float v = vA[nb] + __shfl_xor(vA[nb], 1);
                float x2 = __shfl_xor(v, 2);
                float x4 = __shfl_xor(v, 4);
                float x6 = __shfl_xor(v, 6);
                float h = lstm_combine(v, x2, x4, x6, gate, c0[nb]);
                if ((tid & 7) == 0) hist[nb][t][cell] = h;
            }
            __syncthreads();
        }
    }

    // ================= Phase B: layer 1 =================
    {
        float4 wB[16];
        {
            const float* wsrc = kh ? w_hh1 : w_ih1;
            const float4* p = (const float4*)(wsrc + row * HH);
            #pragma unroll
            for (int k = 0; k < 16; ++k) wB[k] = p[k];
        }
        const float biasB = kh ? 0.0f : (b_ih1[row] + b_hh1[row]);
        float c1[LNB] = {0.0f, 0.0f};

        for (int t = 1; t <= TT; ++t) {
            float vB[LNB];
            #pragma unroll
            for (int nb = 0; nb < LNB; ++nb) {
                const float4* av = kh
                    ? (const float4*)&h1buf[(t - 1) & 1][nb][0]
                    : (const float4*)&hist[nb][t][0];
                float s0 = 0.f, s1 = 0.f, s2 = 0.f, s3 = 0.f;
                #pragma unroll
                for (int k = 0; k < 4; ++k) {
                    s0 += dot4(wB[k],      av[k]);
                    s1 += dot4(wB[4 + k],  av[4 + k]);
                    s2 += dot4(wB[8 + k],  av[8 + k]);
                    s3 += dot4(wB[12 + k], av[12 + k]);
                }
                vB[nb] = biasB + (s0 + s1) + (s2 + s3);
            }
            #pragma unroll
            for (int nb = 0; nb < LNB; ++nb) {
                float v = vB[nb] + __shfl_xor(vB[nb], 1);
                float x2 = __shfl_xor(v, 2);
                float x4 = __shfl_xor(v, 4);
                float x6 = __shfl_xor(v, 6);
                float h = lstm_combine(v, x2, x4, x6, gate, c1[nb]);
                if ((tid & 7) == 0) {
                    h1buf[t & 1][nb][cell] = h;
                    if (t == TT) x_out[(n0 + nb) * HH + cell] = h;
                }
            }
            __syncthreads();
        }
    }
}

// ---------- zero the edge-build counters ----------
__global__ void k_zero(int* __restrict__ cnt, int* __restrict__ nfull)
{
    int i = blockIdx.x * 256 + threadIdx.x;
    if (i < NN) cnt[i] = 0;
    if (i == 0) *nfull = 0;
}

// ---------- build CSC edge list + row_full in one rel_mask scan ----------
__global__ __launch_bounds__(256) void k_edges(
    const float* __restrict__ rel_mask,
    int* __restrict__ cnt, int* __restrict__ csc,
    int* __restrict__ row_full, int* __restrict__ full_list,
    int* __restrict__ nfull)
{
    const int i = blockIdx.x;
    const int tid = threadIdx.x;
    __shared__ int s_any;
    if (tid == 0) s_any = 0;
    __syncthreads();
    bool mine = false;
    for (int j = tid; j < NN; j += 256) {
        float rm = rel_mask[i * NN + j];
        bool edge = (rm == 0.0f);
        mine |= edge;
        if (edge && j != i) {
            int slot = atomicAdd(&cnt[j], 1);
            if (slot < CAP) csc[j * CAP + slot] = i;
        }
    }
    if (mine) atomicOr(&s_any, 1);
    __syncthreads();
    if (tid == 0) {
        row_full[i] = s_any ? 0 : 1;
        if (!s_any) {
            int k = atomicAdd(nfull, 1);
            full_list[k] = i;
        }
    }
}

// ---------- h1 = x @ gat1_W ; es1/ed1 dots ----------
__global__ __launch_bounds__(256) void k_h1(
    const float* __restrict__ x, const float* __restrict__ W,
    const float* __restrict__ a_s, const float* __restrict__ a_d,
    float* __restrict__ h1g, float* __restrict__ es1, float* __restrict__ ed1)
{
    __shared__ float Wl[HH * GATH];
    __shared__ float xl[16 * 65];
    __shared__ float h1l[16 * GATH];
    const int tid = threadIdx.x;
    const int n0 = blockIdx.x * 16;
    for (int idx = tid; idx < HH * GATH; idx += 256) Wl[idx] = W[idx];
    for (int idx = tid; idx < 16 * HH; idx += 256) {
        int ln = idx >> 6, k = idx & 63;
        xl[ln * 65 + k] = x[(n0 + ln) * HH + k];
    }
    __syncthreads();
    const int ln = tid >> 4, jj = tid & 15;
    float acc = 0.0f;
    #pragma unroll 8
    for (int k = 0; k < HH; ++k) acc += xl[ln * 65 + k] * Wl[k * GATH + jj];
    h1g[(n0 + ln) * GATH + jj] = acc;
    h1l[ln * GATH + jj] = acc;
    __syncthreads();
    if (tid < 16) {
        float e_s = 0.0f, e_d = 0.0f;
        #pragma unroll
        for (int t = 0; t < GATH; ++t) {
            float hv = h1l[tid * GATH + t];
            e_s += hv * a_s[t];
            e_d += hv * a_d[t];
        }
        es1[n0 + tid] = e_s;
        ed1[n0 + tid] = e_d;
    }
}

// ---------- GAT1 sparse: 4 cols/block, 4 edge-groups x 16 dims ----------
__global__ __launch_bounds__(256) void k_gat1s(
    const int* __restrict__ cnt, const int* __restrict__ csc,
    const int* __restrict__ row_full, const int* __restrict__ full_list,
    const int* __restrict__ nfull,
    const float* __restrict__ h1g, const float* __restrict__ es1,
    const float* __restrict__ ed1, const float* __restrict__ gat1_b,
    float* __restrict__ hrel)
{
    const int tid = threadIdx.x;
    const int lc = tid >> 6;          // col in block 0..3
    const int grp = (tid >> 4) & 3;   // edge group 0..3
    const int d = tid & 15;           // h-dim 0..15
    const int j = blockIdx.x * 4 + lc;
    const float edj = ed1[j];
    float acc = 0.0f, l = 0.0f;

    const int n = min(cnt[j], CAP);
    const int* lst = csc + j * CAP;
    for (int e = grp; e < n; e += 4) {
        int i = lst[e];
        float p = lrelu_exp(es1[i] + edj);
        l += p;
        acc += p * h1g[i * GATH + d];
    }
    if (grp == 0 && !row_full[j]) {          // self edge (diag)
        float p = lrelu_exp(es1[j] + edj);
        l += p;
        acc += p * h1g[j * GATH + d];
    }
    const int nf = *nfull;                    // full rows adjacent everywhere
    for (int f = grp; f < nf; f += 4) {
        int i = full_list[f];
        float p = lrelu_exp(es1[i] + edj);
        l += p;
        acc += p * h1g[i * GATH + d];
    }

    __shared__ float sacc[4][4][GATH];
    __shared__ float sl[4][4];
    sacc[lc][grp][d] = acc;
    if (d == 0) sl[lc][grp] = l;
    __syncthreads();
    if (grp == 0) {
        float a = sacc[lc][0][d] + sacc[lc][1][d] + sacc[lc][2][d] + sacc[lc][3][d];
        float L = sl[lc][0] + sl[lc][1] + sl[lc][2] + sl[lc][3];
        hrel[j * GATH + d] = fmaxf(a / L + gat1_b[d], 0.0f);
    }
}

// ---------- h2 = hrel @ gat2_W ; es2/ed2 ----------
__global__ __launch_bounds__(256) void k_h2(
    const float* __restrict__ hrel, const float* __restrict__ W2,
    const float* __restrict__ a_s, const float* __restrict__ a_d,
    float* __restrict__ h2g, float* __restrict__ es2, float* __restrict__ ed2)
{
    __shared__ float Wl[GATH * HH];
    __shared__ float hl[4 * 17];
    __shared__ float h2l[4 * HH];
    const int tid = threadIdx.x;
    const int n0 = blockIdx.x * 4;
    for (int idx = tid; idx < GATH * HH; idx += 256) Wl[idx] = W2[idx];
    if (tid < 64) {
        int ln = tid >> 4, k = tid & 15;
        hl[ln * 17 + k] = hrel[(n0 + ln) * GATH + k];
    }
    __syncthreads();
    const int ln = tid >> 6, jj = tid & 63;
    float acc = 0.0f;
    #pragma unroll
    for (int k = 0; k < GATH; ++k) acc += hl[ln * 17 + k] * Wl[k * HH + jj];
    h2g[(n0 + ln) * HH + jj] = acc;
    h2l[ln * HH + jj] = acc;
    __syncthreads();
    if (tid < 4) {
        float e_s = 0.0f, e_d = 0.0f;
        #pragma unroll 16
        for (int t = 0; t < HH; ++t) {
            float hv = h2l[tid * HH + t];
            e_s += hv * a_s[t];
            e_d += hv * a_d[t];
        }
        es2[n0 + tid] = e_s;
        ed2[n0 + tid] = e_d;
    }
}

// ---------- GAT2 sparse + fc + leaky_relu: 1 col/block ----------
__global__ __launch_bounds__(256) void k_gat2s(
    const int* __restrict__ cnt, const int* __restrict__ csc,
    const int* __restrict__ row_full, const int* __restrict__ full_list,
    const int* __restrict__ nfull,
    const float* __restrict__ h2g, const float* __restrict__ es2,
    const float* __restrict__ ed2, const float* __restrict__ gat2_b,
    const float* __restrict__ fc_W, const float* __restrict__ fc_b,
    float* __restrict__ out)
{
    const int tid = threadIdx.x;
    const int grp = tid >> 6;         // edge group 0..3
    const int d = tid & 63;           // h-dim 0..63
    const int j = blockIdx.x;
    const float edj = ed2[j];
    float acc = 0.0f, l = 0.0f;

    const int n = min(cnt[j], CAP);
    const int* lst = csc + j * CAP;
    for (int e = grp; e < n; e += 4) {
        int i = lst[e];
        float p = lrelu_exp(es2[i] + edj);
        l += p;
        acc += p * h2g[i * HH + d];
    }
    if (grp == 0 && !row_full[j]) {
        float p = lrelu_exp(es2[j] + edj);
        l += p;
        acc += p * h2g[j * HH + d];
    }
    const int nf = *nfull;
    for (int f = grp; f < nf; f += 4) {
        int i = full_list[f];
        float p = lrelu_exp(es2[i] + edj);
        l += p;
        acc += p * h2g[i * HH + d];
    }

    __shared__ float sacc[4][HH];
    __shared__ float sl[4];
    sacc[grp][d] = acc;
    if (d == 0) sl[grp] = l;
    __syncthreads();
    if (grp == 0) {                    // tid 0..63 = one wave
        float a = sacc[0][d] + sacc[1][d] + sacc[2][d] + sacc[3][d];
        float L = sl[0] + sl[1] + sl[2] + sl[3];
        float v = a / L + gat2_b[d];
        float t = v * fc_W[d];
        #pragma unroll
        for (int off = 32; off >= 1; off >>= 1)
            t += __shfl_down(t, off, 64);
        if (d == 0) {
            float r = t + fc_b[0];
            out[j] = (r > 0.0f) ? r : 0.2f * r;
        }
    }
}

extern "C" void kernel_launch(void* const* d_in, const int* in_sizes, int n_in,
                              void* d_out, int out_size, void* d_ws, size_t ws_size,
                              hipStream_t stream)
{
    const float* inputs   = (const float*)d_in[0];
    // d_in[1] (relation), d_in[3] (rel_w_W), d_in[4] (rel_w_b) are dead:
    // softmax(rel_mask + weight) > 0 depends only on rel_mask.
    const float* rel_mask = (const float*)d_in[2];
    const float* w_ih0 = (const float*)d_in[5];
    const float* w_hh0 = (const float*)d_in[6];
    const float* b_ih0 = (const float*)d_in[7];
    const float* b_hh0 = (const float*)d_in[8];
    const float* w_ih1 = (const float*)d_in[9];
    const float* w_hh1 = (const float*)d_in[10];
    const float* b_ih1 = (const float*)d_in[11];
    const float* b_hh1 = (const float*)d_in[12];
    const float* gat1_W  = (const float*)d_in[13];
    const float* gat1_as = (const float*)d_in[14];
    const float* gat1_ad = (const float*)d_in[15];
    const float* gat1_b  = (const float*)d_in[16];
    const float* gat2_W  = (const float*)d_in[17];
    const float* gat2_as = (const float*)d_in[18];
    const float* gat2_ad = (const float*)d_in[19];
    const float* gat2_b  = (const float*)d_in[20];
    const float* fc_W = (const float*)d_in[21];
    const float* fc_b = (const float*)d_in[22];
    float* out = (float*)d_out;

    float* ws = (float*)d_ws;
    float* x_out = ws;                       // 2048*64
    float* h1g = x_out + NN * HH;            // 2048*16
    float* es1 = h1g + NN * GATH;            // 2048
    float* ed1 = es1 + NN;                   // 2048
    float* hrel = ed1 + NN;                  // 2048*16
    float* h2g = hrel + NN * GATH;           // 2048*64
    float* es2 = h2g + NN * HH;              // 2048
    float* ed2 = es2 + NN;                   // 2048
    int* cnt = (int*)(ed2 + NN);             // 2048
    int* row_full = cnt + NN;                // 2048
    int* full_list = row_full + NN;          // 2048
    int* nfull = full_list + NN;             // 1 (+pad)
    int* csc = nfull + 8;                    // 2048*CAP = 2 MB

    k_zero<<<(NN + 255) / 256, 256, 0, stream>>>(cnt, nfull);
    k_edges<<<NN, 256, 0, stream>>>(rel_mask, cnt, csc, row_full, full_list, nfull);
    k_lstm<<<NN / LNB, 512, 0, stream>>>(inputs, w_ih0, w_hh0, b_ih0, b_hh0,
                                         w_ih1, w_hh1, b_ih1, b_hh1, x_out);
    k_h1<<<NN / 16, 256, 0, stream>>>(x_out, gat1_W, gat1_as, gat1_ad, h1g, es1, ed1);
    k_gat1s<<<NN / 4, 256, 0, stream>>>(cnt, csc, row_full, full_list, nfull,
                                        h1g, es1, ed1, gat1_b, hrel);
    k_h2<<<NN / 4, 256, 0, stream>>>(hrel, gat2_W, gat2_as, gat2_ad, h2g, es2, ed2);
    k_gat2s<<<NN, 256, 0, stream>>>(cnt, csc, row_full, full_list, nfull,
                                    h2g, es2, ed2, gat2_b, fc_W, fc_b, out);
}

// Round 2
// 753.667 us; speedup vs baseline: 1.0052x; 1.0052x over previous
//
#include <hip/hip_runtime.h>
#include <math.h>

#define NN 2048
#define TT 32
#define FIN 5
#define HH 64
#define G4 256     // 4*H
#define GATH 16
#define CAP 256    // max CSC edges/column: mean 102, sigma ~10 -> +15 sigma safe
#define HP 68      // padded hist row: [32 floats][4 pad][32 floats] -> kh halves
                   // sit 144B apart = disjoint bank groups (128B would alias)

// ---------- helpers ----------
__device__ __forceinline__ float sigf(float x) {
    return 1.0f / (1.0f + __expf(-x));
}
__device__ __forceinline__ float tanh_fast(float x) {
    x = fminf(fmaxf(x, -15.0f), 15.0f);
    float t = __expf(2.0f * x);
    return (t - 1.0f) / (t + 1.0f);
}
__device__ __forceinline__ float dot4(float4 a, float4 b) {
    return a.x * b.x + a.y * b.y + a.z * b.z + a.w * b.w;
}
__device__ __forceinline__ float lrelu_exp(float x) {
    x = (x > 0.0f) ? x : 0.2f * x;
    return __expf(x);
}
__device__ __forceinline__ int pidx(int c) {   // cell -> padded offset
    return c + ((c >> 5) << 2);
}

// gate-collect + cell update. v = own gate's full value; x2/x4/x6 = values of
// gates at lane-xor 2/4/6. Mapping: value of gate j sits at xor ((gate^j)<<1).
__device__ __forceinline__ float lstm_combine(float v, float x2, float x4,
                                              float x6, int gate, float& c)
{
    float gi = (gate == 0) ? v  : (gate == 1) ? x2 : (gate == 2) ? x4 : x6;
    float gf = (gate == 0) ? x2 : (gate == 1) ? v  : (gate == 2) ? x6 : x4;
    float gg = (gate == 0) ? x4 : (gate == 1) ? x6 : (gate == 2) ? v  : x2;
    float go = (gate == 0) ? x6 : (gate == 1) ? x4 : (gate == 2) ? x2 : v;
    c = sigf(gf) * c + sigf(gi) * tanh_fast(gg);
    return sigf(go) * tanh_fast(c);
}

// ---------- fused 2-layer LSTM ----------
// R9: same 512-thread K-split remap as R8 (kh=tid&1, gate=(tid>>1)&3,
// cell=tid>>3; gate exchange = shfl_xor; 1 barrier/step), but:
//  * __launch_bounds__(512, 2): second arg is honored as BLOCKS/CU here
//    (R8's (512,4) -> 32 waves/CU -> 64-VGPR cap -> 330 MB of scratch spill,
//    FETCH 120 MB / WRITE 208 MB). 2 blocks/CU -> 128-VGPR cap; phase-B
//    weights (64 VGPRs) + working set (~45) fit -> zero spill.
//  * hist/h1buf rows padded to 68 floats, halves at +0/+36: kills the
//    ubiquitous 2-way ds_read_b128 conflict (halves were 128B apart).
#define LNB 2
__global__ __launch_bounds__(512, 2)
void k_lstm(
    const float* __restrict__ inputs,
    const float* __restrict__ w_ih0, const float* __restrict__ w_hh0,
    const float* __restrict__ b_ih0, const float* __restrict__ b_hh0,
    const float* __restrict__ w_ih1, const float* __restrict__ w_hh1,
    const float* __restrict__ b_ih1, const float* __restrict__ b_hh1,
    float* __restrict__ x_out)
{
    __shared__ float x_lds[LNB][TT * FIN];     // 320 f
    __shared__ float hist[LNB][TT + 1][HP];    // 4488 f = 17.95 KB
    __shared__ float h1buf[2][LNB][HP];        // 272 f (ping-pong: 1 barrier/t)

    const int tid  = threadIdx.x;
    const int kh   = tid & 1;          // K-half
    const int gate = (tid >> 1) & 3;   // i/f/g/o
    const int cell = tid >> 3;         // 0..63
    const int row  = gate * HH + cell; // gate row 0..255
    const int n0   = blockIdx.x * LNB;

    for (int idx = tid; idx < LNB * TT * FIN; idx += 512)
        ((float*)x_lds)[idx] = inputs[n0 * (TT * FIN) + idx];
    if (tid < LNB * HH) {
        hist[tid >> 6][0][pidx(tid & 63)] = 0.0f;
        h1buf[0][tid >> 6][pidx(tid & 63)] = 0.0f;
    }

    // ================= Phase A: layer 0 =================
    {
        float4 wA[8];
        {
            const float4* p = (const float4*)(w_hh0 + row * HH + kh * 32);
            #pragma unroll
            for (int k = 0; k < 8; ++k) wA[k] = p[k];
        }
        float xw0 = 0.f, xw1 = 0.f, xw2 = 0.f, xw3 = 0.f, xw4 = 0.f;
        float biasA = 0.f;
        if (kh == 0) {
            xw0 = w_ih0[row * FIN + 0];
            xw1 = w_ih0[row * FIN + 1];
            xw2 = w_ih0[row * FIN + 2];
            xw3 = w_ih0[row * FIN + 3];
            xw4 = w_ih0[row * FIN + 4];
            biasA = b_ih0[row] + b_hh0[row];
        }
        float c0[LNB] = {0.0f, 0.0f};

        __syncthreads();

        for (int t = 1; t <= TT; ++t) {
            float vA[LNB];
            #pragma unroll
            for (int nb = 0; nb < LNB; ++nb) {
                // kh half lives at +0 / +36 floats (contiguous 8 f4 each)
                const float4* hv = (const float4*)&hist[nb][t - 1][kh * 36];
                float s0 = 0.f, s1 = 0.f, s2 = 0.f, s3 = 0.f;
                #pragma unroll
                for (int k = 0; k < 2; ++k) {
                    s0 += dot4(wA[k],     hv[k]);
                    s1 += dot4(wA[2 + k], hv[2 + k]);
                    s2 += dot4(wA[4 + k], hv[4 + k]);
                    s3 += dot4(wA[6 + k], hv[6 + k]);
                }
                float s = (s0 + s1) + (s2 + s3);
                if (kh == 0) {
                    const float* xv = &x_lds[nb][(t - 1) * FIN];
                    s += biasA + xw0 * xv[0] + xw1 * xv[1] + xw2 * xv[2] +
                         xw3 * xv[3] + xw4 * xv[4];
                }
                vA[nb] = s;
            }
            #pragma unroll
            for (int nb = 0; nb < LNB; ++nb) {
                float v = vA[nb] + __shfl_xor(vA[nb], 1);
                float x2 = __shfl_xor(v, 2);
                float x4 = __shfl_xor(v, 4);
                float x6 = __shfl_xor(v, 6);
                float h = lstm_combine(v, x2, x4, x6, gate, c0[nb]);
                if ((tid & 7) == 0) hist[nb][t][pidx(cell)] = h;
            }
            __syncthreads();
        }
    }

    // ================= Phase B: layer 1 =================
    {
        float4 wB[16];
        {
            const float* wsrc = kh ? w_hh1 : w_ih1;
            const float4* p = (const float4*)(wsrc + row * HH);
            #pragma unroll
            for (int k = 0; k < 16; ++k) wB[k] = p[k];
        }
        const float biasB = kh ? 0.0f : (b_ih1[row] + b_hh1[row]);
        float c1[LNB] = {0.0f, 0.0f};

        for (int t = 1; t <= TT; ++t) {
            float vB[LNB];
            #pragma unroll
            for (int nb = 0; nb < LNB; ++nb) {
                // both sources share the padded [32|pad|32] row layout:
                // logical f4 j lives at physical f4 (j<8 ? j : j+1)
                const float4* av = kh
                    ? (const float4*)&h1buf[(t - 1) & 1][nb][0]
                    : (const float4*)&hist[nb][t][0];
                float s0 = 0.f, s1 = 0.f, s2 = 0.f, s3 = 0.f;
                #pragma unroll
                for (int k = 0; k < 4; ++k) {
                    s0 += dot4(wB[k],      av[k]);
                    s1 += dot4(wB[4 + k],  av[4 + k]);
                    s2 += dot4(wB[8 + k],  av[9 + k]);
                    s3 += dot4(wB[12 + k], av[13 + k]);
                }
                vB[nb] = biasB + (s0 + s1) + (s2 + s3);
            }
            #pragma unroll
            for (int nb = 0; nb < LNB; ++nb) {
                float v = vB[nb] + __shfl_xor(vB[nb], 1);
                float x2 = __shfl_xor(v, 2);
                float x4 = __shfl_xor(v, 4);
                float x6 = __shfl_xor(v, 6);
                float h = lstm_combine(v, x2, x4, x6, gate, c1[nb]);
                if ((tid & 7) == 0) {
                    h1buf[t & 1][nb][pidx(cell)] = h;
                    if (t == TT) x_out[(n0 + nb) * HH + cell] = h;
                }
            }
            __syncthreads();
        }
    }
}

// ---------- zero the edge-build counters ----------
__global__ void k_zero(int* __restrict__ cnt, int* __restrict__ nfull)
{
    int i = blockIdx.x * 256 + threadIdx.x;
    if (i < NN) cnt[i] = 0;
    if (i == 0) *nfull = 0;
}

// ---------- build CSC edge list + row_full in one rel_mask scan ----------
__global__ __launch_bounds__(256) void k_edges(
    const float* __restrict__ rel_mask,
    int* __restrict__ cnt, int* __restrict__ csc,
    int* __restrict__ row_full, int* __restrict__ full_list,
    int* __restrict__ nfull)
{
    const int i = blockIdx.x;
    const int tid = threadIdx.x;
    __shared__ int s_any;
    if (tid == 0) s_any = 0;
    __syncthreads();
    bool mine = false;
    for (int j = tid; j < NN; j += 256) {
        float rm = rel_mask[i * NN + j];
        bool edge = (rm == 0.0f);
        mine |= edge;
        if (edge && j != i) {
            int slot = atomicAdd(&cnt[j], 1);
            if (slot < CAP) csc[j * CAP + slot] = i;
        }
    }
    if (mine) atomicOr(&s_any, 1);
    __syncthreads();
    if (tid == 0) {
        row_full[i] = s_any ? 0 : 1;
        if (!s_any) {
            int k = atomicAdd(nfull, 1);
            full_list[k] = i;
        }
    }
}

// ---------- h1 = x @ gat1_W ; es1/ed1 dots ----------
__global__ __launch_bounds__(256) void k_h1(
    const float* __restrict__ x, const float* __restrict__ W,
    const float* __restrict__ a_s, const float* __restrict__ a_d,
    float* __restrict__ h1g, float* __restrict__ es1, float* __restrict__ ed1)
{
    __shared__ float Wl[HH * GATH];
    __shared__ float xl[16 * 65];
    __shared__ float h1l[16 * GATH];
    const int tid = threadIdx.x;
    const int n0 = blockIdx.x * 16;
    for (int idx = tid; idx < HH * GATH; idx += 256) Wl[idx] = W[idx];
    for (int idx = tid; idx < 16 * HH; idx += 256) {
        int ln = idx >> 6, k = idx & 63;
        xl[ln * 65 + k] = x[(n0 + ln) * HH + k];
    }
    __syncthreads();
    const int ln = tid >> 4, jj = tid & 15;
    float acc = 0.0f;
    #pragma unroll 8
    for (int k = 0; k < HH; ++k) acc += xl[ln * 65 + k] * Wl[k * GATH + jj];
    h1g[(n0 + ln) * GATH + jj] = acc;
    h1l[ln * GATH + jj] = acc;
    __syncthreads();
    if (tid < 16) {
        float e_s = 0.0f, e_d = 0.0f;
        #pragma unroll
        for (int t = 0; t < GATH; ++t) {
            float hv = h1l[tid * GATH + t];
            e_s += hv * a_s[t];
            e_d += hv * a_d[t];
        }
        es1[n0 + tid] = e_s;
        ed1[n0 + tid] = e_d;
    }
}

// ---------- GAT1 sparse: 4 cols/block, 4 edge-groups x 16 dims ----------
__global__ __launch_bounds__(256) void k_gat1s(
    const int* __restrict__ cnt, const int* __restrict__ csc,
    const int* __restrict__ row_full, const int* __restrict__ full_list,
    const int* __restrict__ nfull,
    const float* __restrict__ h1g, const float* __restrict__ es1,
    const float* __restrict__ ed1, const float* __restrict__ gat1_b,
    float* __restrict__ hrel)
{
    const int tid = threadIdx.x;
    const int lc = tid >> 6;          // col in block 0..3
    const int grp = (tid >> 4) & 3;   // edge group 0..3
    const int d = tid & 15;           // h-dim 0..15
    const int j = blockIdx.x * 4 + lc;
    const float edj = ed1[j];
    float acc = 0.0f, l = 0.0f;

    const int n = min(cnt[j], CAP);
    const int* lst = csc + j * CAP;
    for (int e = grp; e < n; e += 4) {
        int i = lst[e];
        float p = lrelu_exp(es1[i] + edj);
        l += p;
        acc += p * h1g[i * GATH + d];
    }
    if (grp == 0 && !row_full[j]) {          // self edge (diag)
        float p = lrelu_exp(es1[j] + edj);
        l += p;
        acc += p * h1g[j * GATH + d];
    }
    const int nf = *nfull;                    // full rows adjacent everywhere
    for (int f = grp; f < nf; f += 4) {
        int i = full_list[f];
        float p = lrelu_exp(es1[i] + edj);
        l += p;
        acc += p * h1g[i * GATH + d];
    }

    __shared__ float sacc[4][4][GATH];
    __shared__ float sl[4][4];
    sacc[lc][grp][d] = acc;
    if (d == 0) sl[lc][grp] = l;
    __syncthreads();
    if (grp == 0) {
        float a = sacc[lc][0][d] + sacc[lc][1][d] + sacc[lc][2][d] + sacc[lc][3][d];
        float L = sl[lc][0] + sl[lc][1] + sl[lc][2] + sl[lc][3];
        hrel[j * GATH + d] = fmaxf(a / L + gat1_b[d], 0.0f);
    }
}

// ---------- h2 = hrel @ gat2_W ; es2/ed2 ----------
__global__ __launch_bounds__(256) void k_h2(
    const float* __restrict__ hrel, const float* __restrict__ W2,
    const float* __restrict__ a_s, const float* __restrict__ a_d,
    float* __restrict__ h2g, float* __restrict__ es2, float* __restrict__ ed2)
{
    __shared__ float Wl[GATH * HH];
    __shared__ float hl[4 * 17];
    __shared__ float h2l[4 * HH];
    const int tid = threadIdx.x;
    const int n0 = blockIdx.x * 4;
    for (int idx = tid; idx < GATH * HH; idx += 256) Wl[idx] = W2[idx];
    if (tid < 64) {
        int ln = tid >> 4, k = tid & 15;
        hl[ln * 17 + k] = hrel[(n0 + ln) * GATH + k];
    }
    __syncthreads();
    const int ln = tid >> 6, jj = tid & 63;
    float acc = 0.0f;
    #pragma unroll
    for (int k = 0; k < GATH; ++k) acc += hl[ln * 17 + k] * Wl[k * HH + jj];
    h2g[(n0 + ln) * HH + jj] = acc;
    h2l[ln * HH + jj] = acc;
    __syncthreads();
    if (tid < 4) {
        float e_s = 0.0f, e_d = 0.0f;
        #pragma unroll 16
        for (int t = 0; t < HH; ++t) {
            float hv = h2l[tid * HH + t];
            e_s += hv * a_s[t];
            e_d += hv * a_d[t];
        }
        es2[n0 + tid] = e_s;
        ed2[n0 + tid] = e_d;
    }
}

// ---------- GAT2 sparse + fc + leaky_relu: 1 col/block ----------
__global__ __launch_bounds__(256) void k_gat2s(
    const int* __restrict__ cnt, const int* __restrict__ csc,
    const int* __restrict__ row_full, const int* __restrict__ full_list,
    const int* __restrict__ nfull,
    const float* __restrict__ h2g, const float* __restrict__ es2,
    const float* __restrict__ ed2, const float* __restrict__ gat2_b,
    const float* __restrict__ fc_W, const float* __restrict__ fc_b,
    float* __restrict__ out)
{
    const int tid = threadIdx.x;
    const int grp = tid >> 6;         // edge group 0..3
    const int d = tid & 63;           // h-dim 0..63
    const int j = blockIdx.x;
    const float edj = ed2[j];
    float acc = 0.0f, l = 0.0f;

    const int n = min(cnt[j], CAP);
    const int* lst = csc + j * CAP;
    for (int e = grp; e < n; e += 4) {
        int i = lst[e];
        float p = lrelu_exp(es2[i] + edj);
        l += p;
        acc += p * h2g[i * HH + d];
    }
    if (grp == 0 && !row_full[j]) {
        float p = lrelu_exp(es2[j] + edj);
        l += p;
        acc += p * h2g[j * HH + d];
    }
    const int nf = *nfull;
    for (int f = grp; f < nf; f += 4) {
        int i = full_list[f];
        float p = lrelu_exp(es2[i] + edj);
        l += p;
        acc += p * h2g[i * HH + d];
    }

    __shared__ float sacc[4][HH];
    __shared__ float sl[4];
    sacc[grp][d] = acc;
    if (d == 0) sl[grp] = l;
    __syncthreads();
    if (grp == 0) {                    // tid 0..63 = one wave
        float a = sacc[0][d] + sacc[1][d] + sacc[2][d] + sacc[3][d];
        float L = sl[0] + sl[1] + sl[2] + sl[3];
        float v = a / L + gat2_b[d];
        float t = v * fc_W[d];
        #pragma unroll
        for (int off = 32; off >= 1; off >>= 1)
            t += __shfl_down(t, off, 64);
        if (d == 0) {
            float r = t + fc_b[0];
            out[j] = (r > 0.0f) ? r : 0.2f * r;
        }
    }
}

extern "C" void kernel_launch(void* const* d_in, const int* in_sizes, int n_in,
                              void* d_out, int out_size, void* d_ws, size_t ws_size,
                              hipStream_t stream)
{
    const float* inputs   = (const float*)d_in[0];
    // d_in[1] (relation), d_in[3] (rel_w_W), d_in[4] (rel_w_b) are dead:
    // softmax(rel_mask + weight) > 0 depends only on rel_mask.
    const float* rel_mask = (const float*)d_in[2];
    const float* w_ih0 = (const float*)d_in[5];
    const float* w_hh0 = (const float*)d_in[6];
    const float* b_ih0 = (const float*)d_in[7];
    const float* b_hh0 = (const float*)d_in[8];
    const float* w_ih1 = (const float*)d_in[9];
    const float* w_hh1 = (const float*)d_in[10];
    const float* b_ih1 = (const float*)d_in[11];
    const float* b_hh1 = (const float*)d_in[12];
    const float* gat1_W  = (const float*)d_in[13];
    const float* gat1_as = (const float*)d_in[14];
    const float* gat1_ad = (const float*)d_in[15];
    const float* gat1_b  = (const float*)d_in[16];
    const float* gat2_W  = (const float*)d_in[17];
    const float* gat2_as = (const float*)d_in[18];
    const float* gat2_ad = (const float*)d_in[19];
    const float* gat2_b  = (const float*)d_in[20];
    const float* fc_W = (const float*)d_in[21];
    const float* fc_b = (const float*)d_in[22];
    float* out = (float*)d_out;

    float* ws = (float*)d_ws;
    float* x_out = ws;                       // 2048*64
    float* h1g = x_out + NN * HH;            // 2048*16
    float* es1 = h1g + NN * GATH;            // 2048
    float* ed1 = es1 + NN;                   // 2048
    float* hrel = ed1 + NN;                  // 2048*16
    float* h2g = hrel + NN * GATH;           // 2048*64
    float* es2 = h2g + NN * HH;              // 2048
    float* ed2 = es2 + NN;                   // 2048
    int* cnt = (int*)(ed2 + NN);             // 2048
    int* row_full = cnt + NN;                // 2048
    int* full_list = row_full + NN;          // 2048
    int* nfull = full_list + NN;             // 1 (+pad)
    int* csc = nfull + 8;                    // 2048*CAP = 2 MB

    k_zero<<<(NN + 255) / 256, 256, 0, stream>>>(cnt, nfull);
    k_edges<<<NN, 256, 0, stream>>>(rel_mask, cnt, csc, row_full, full_list, nfull);
    k_lstm<<<NN / LNB, 512, 0, stream>>>(inputs, w_ih0, w_hh0, b_ih0, b_hh0,
                                         w_ih1, w_hh1, b_ih1, b_hh1, x_out);
    k_h1<<<NN / 16, 256, 0, stream>>>(x_out, gat1_W, gat1_as, gat1_ad, h1g, es1, ed1);
    k_gat1s<<<NN / 4, 256, 0, stream>>>(cnt, csc, row_full, full_list, nfull,
                                        h1g, es1, ed1, gat1_b, hrel);
    k_h2<<<NN / 4, 256, 0, stream>>>(hrel, gat2_W, gat2_as, gat2_ad, h2g, es2, ed2);
    k_gat2s<<<NN, 256, 0, stream>>>(cnt, csc, row_full, full_list, nfull,
                                    h2g, es2, ed2, gat2_b, fc_W, fc_b, out);
}